// Round 11
// baseline (662.768 us; speedup 1.0000x reference)
//
#include <hip/hip_runtime.h>
#include <math.h>

#define NB 256      // events
#define NSV 64
#define NTRK 512
#define NPFC 512
#define KNN 8
#define HD 32

typedef float v2f __attribute__((ext_vector_type(2)));

__device__ __forceinline__ float elu_f(float x) {
    return x > 0.f ? x : __expf(x) - 1.f;
}

// Branchless sorted top-8 insert (ascending val, lower-index tie-break via
// strict <; ascending-s scan order). Flat v_cmp + v_cndmask codegen.
__device__ __forceinline__ void ins8(float dv, int s, float* val, int* idx) {
    bool c0 = dv < val[0], c1 = dv < val[1], c2 = dv < val[2], c3 = dv < val[3];
    bool c4 = dv < val[4], c5 = dv < val[5], c6 = dv < val[6], c7 = dv < val[7];
    val[7] = c6 ? val[6] : (c7 ? dv : val[7]);
    idx[7] = c6 ? idx[6] : (c7 ? s  : idx[7]);
    val[6] = c5 ? val[5] : (c6 ? dv : val[6]);
    idx[6] = c5 ? idx[5] : (c6 ? s  : idx[6]);
    val[5] = c4 ? val[4] : (c5 ? dv : val[5]);
    idx[5] = c4 ? idx[4] : (c5 ? s  : idx[5]);
    val[4] = c3 ? val[3] : (c4 ? dv : val[4]);
    idx[4] = c3 ? idx[3] : (c4 ? s  : idx[4]);
    val[3] = c2 ? val[2] : (c3 ? dv : val[3]);
    idx[3] = c2 ? idx[2] : (c3 ? s  : idx[3]);
    val[2] = c1 ? val[1] : (c2 ? dv : val[2]);
    idx[2] = c1 ? idx[1] : (c2 ? s  : idx[2]);
    val[1] = c0 ? val[0] : (c1 ? dv : val[1]);
    idx[1] = c0 ? idx[0] : (c1 ? s  : idx[1]);
    val[0] = c0 ? dv : val[0];
    idx[0] = c0 ? s  : idx[0];
}

// ---------------- encoder body ----------------
template<int FIN>
__device__ void encode_body(const float* __restrict__ x,
                            const float* __restrict__ W1, const float* __restrict__ b1,
                            const float* __restrict__ W2, const float* __restrict__ b2,
                            float* __restrict__ out, int blk, int n_nodes)
{
    __shared__ float sW1[FIN * 32];
    __shared__ float sW2[32 * 32];
    __shared__ float sb1[32], sb2[32];
    __shared__ float sx[8][FIN];
    __shared__ float sh[8][32];
    int tid = threadIdx.x;
    for (int i = tid; i < FIN * 32; i += 256) sW1[i] = W1[i];
    for (int i = tid; i < 32 * 32; i += 256) sW2[i] = W2[i];
    if (tid < 32) { sb1[tid] = b1[tid]; sb2[tid] = b2[tid]; }
    int ln = tid >> 5, c = tid & 31;
    for (int it = 0; it < 4; it++) {
        int node0 = blk * 32 + it * 8;
        __syncthreads();
        for (int i = tid; i < 8 * FIN; i += 256) {
            int nn = i / FIN, f = i - nn * FIN;
            int node = node0 + nn;
            sx[nn][f] = (node < n_nodes) ? x[(size_t)node * FIN + f] : 0.f;
        }
        __syncthreads();
        float h = sb1[c];
#pragma unroll
        for (int f = 0; f < FIN; f++) h = fmaf(sx[ln][f], sW1[f * 32 + c], h);
        h = elu_f(h);
        sh[ln][c] = h;
        __syncthreads();
        float o = sb2[c];
#pragma unroll
        for (int k = 0; k < 32; k++) o = fmaf(sh[ln][k], sW2[k * 32 + c], o);
        o = elu_f(o);
        int node = node0 + ln;
        if (node < n_nodes) out[(size_t)node * 32 + c] = o;
    }
}

// ---------------- fused encoders + weight prep (1 launch) ----------------
__global__ __launch_bounds__(256) void encode_all_kernel(
    const float* __restrict__ x_sv, const float* __restrict__ x_trk, const float* __restrict__ x_pfc,
    const float* __restrict__ sv_W1, const float* __restrict__ sv_b1,
    const float* __restrict__ sv_W2, const float* __restrict__ sv_b2,
    const float* __restrict__ trk_W1, const float* __restrict__ trk_b1,
    const float* __restrict__ trk_W2, const float* __restrict__ trk_b2,
    const float* __restrict__ pfc_W1, const float* __restrict__ pfc_b1,
    const float* __restrict__ pfc_W2, const float* __restrict__ pfc_b2,
    const float* __restrict__ conv_W, const float* __restrict__ conv_b,
    float* __restrict__ sv_enc, float* __restrict__ trk_enc, float* __restrict__ pfc_enc,
    float* __restrict__ wd, float* __restrict__ w2h, float* __restrict__ bb)
{
    int bid = blockIdx.x;
    if (bid < 512) {
        encode_body<14>(x_sv, sv_W1, sv_b1, sv_W2, sv_b2, sv_enc, bid, NB * NSV);
    } else if (bid < 4608) {
        encode_body<30>(x_trk, trk_W1, trk_b1, trk_W2, trk_b2, trk_enc, bid - 512, NB * NTRK);
    } else if (bid < 8704) {
        encode_body<10>(x_pfc, pfc_W1, pfc_b1, pfc_W2, pfc_b2, pfc_enc, bid - 4608, NB * NPFC);
    } else {
        int tid = threadIdx.x;
        for (int i = tid; i < 1024; i += 256) {
            float lo = conv_W[i], hi = conv_W[1024 + i];
            wd[i] = lo - hi;
            w2h[i] = hi;
        }
        if (tid < 32) bb[tid] = conv_b[tid];
    }
}

// ---------------- 64-row kNN scan core (pk-fma distance chains) -----------
// Scans 64 staged src rows for 2 dst nodes per lane. Accumulator pairing
// {a0,a1},{a2,a3} with __builtin_elementwise_fma -> v_pk_fma_f32, chains
// bit-identical to the validated scalar version (a0:x, a1:y, a2:z, a3:w;
// dv = nrm - 2*((a0+a1)+(a2+a3))).
__device__ __forceinline__ void knn64_scan(
    const float4* __restrict__ s_src, const float* __restrict__ s_nrm,
    const v2f* __restrict__ xd0, const v2f* __restrict__ xd1,
    float* val0, int* idx0, float* val1, int* idx1)
{
    for (int s = 0; s < 64; s++) {
        v2f A01 = {0.f, 0.f}, A23 = {0.f, 0.f};
        v2f C01 = {0.f, 0.f}, C23 = {0.f, 0.f};
#pragma unroll
        for (int q = 0; q < 8; q++) {
            float4 v = s_src[s * 8 + q];
            v2f vxy = {v.x, v.y};
            v2f vzw = {v.z, v.w};
            A01 = __builtin_elementwise_fma(xd0[2*q],   vxy, A01);
            A23 = __builtin_elementwise_fma(xd0[2*q+1], vzw, A23);
            C01 = __builtin_elementwise_fma(xd1[2*q],   vxy, C01);
            C23 = __builtin_elementwise_fma(xd1[2*q+1], vzw, C23);
        }
        float nrm = s_nrm[s];
        float dv0 = nrm - 2.f * ((A01.x + A01.y) + (A23.x + A23.y));
        float dv1 = nrm - 2.f * ((C01.x + C01.y) + (C23.x + C23.y));
        ins8(dv0, s, val0, idx0);
        ins8(dv1, s, val1, idx1);
    }
}

// load one dst row into v2f[16] fragments
__device__ __forceinline__ void load_xd(const float4* xi, v2f* xd) {
#pragma unroll
    for (int q = 0; q < 8; q++) {
        float4 v = xi[q];
        xd[2*q]   = (v2f){v.x, v.y};
        xd[2*q+1] = (v2f){v.z, v.w};
    }
}

// ---------------- small kNN (conv1, NS=64): final idx directly ------------
__device__ void knn_small_body(const float* __restrict__ src, const float* __restrict__ dst,
                               int* __restrict__ idx_out, int b)
{
    __shared__ float4 s_src[64 * 8];
    __shared__ float  s_nrm[64];
    int tid = threadIdx.x;
    int lane = tid & 63;
    int wave = tid >> 6;

    const float4* src4 = (const float4*)(src + (size_t)b * 64 * 32);
    for (int i = tid; i < 64 * 8; i += 256) s_src[i] = src4[i];
    __syncthreads();
    if (tid < 64) {
        float a = 0.f;
#pragma unroll
        for (int q = 0; q < 8; q++) {
            float4 v = s_src[tid * 8 + q];
            a = fmaf(v.x, v.x, a); a = fmaf(v.y, v.y, a);
            a = fmaf(v.z, v.z, a); a = fmaf(v.w, v.w, a);
        }
        s_nrm[tid] = a;
    }
    __syncthreads();

    int t0 = wave * 64 + lane;
    int t1 = t0 + 256;
    v2f xd0[16], xd1[16];
    load_xd((const float4*)(dst + ((size_t)b * 512 + t0) * 32), xd0);
    load_xd((const float4*)(dst + ((size_t)b * 512 + t1) * 32), xd1);

    float val0[KNN], val1[KNN]; int idx0[KNN], idx1[KNN];
#pragma unroll
    for (int k = 0; k < KNN; k++) {
        val0[k] = 3.0e38f; idx0[k] = 0;
        val1[k] = 3.0e38f; idx1[k] = 0;
    }
    knn64_scan(s_src, s_nrm, xd0, xd1, val0, idx0, val1, idx1);

    int* o0 = idx_out + ((size_t)b * 512 + t0) * 8;
    int* o1 = idx_out + ((size_t)b * 512 + t1) * 8;
#pragma unroll
    for (int k = 0; k < KNN; k++) { o0[k] = idx0[k]; o1[k] = idx1[k]; }
}

// ---------------- split kNN (NS=512, 8-way src split, HR=64) --------------
// kid = (event<<3)|part. Block scans rows [part*64, part*64+64) for all 512
// dst. 8.7KB LDS, uniform 64-row bodies (no straggler imbalance). Partial
// sorted top-8 (exact fp32 + u16 global idx); gather merges parts ascending
// (exact single-scan tie semantics).
__device__ void knn_split_body(const float* __restrict__ src, const float* __restrict__ dst,
                               float* __restrict__ pval, unsigned int* __restrict__ pidx,
                               int kid)
{
    __shared__ float4 s_src[64 * 8];
    __shared__ float  s_nrm[64];
    int b = kid >> 3, part = kid & 7;
    int tid = threadIdx.x;
    int lane = tid & 63;
    int wave = tid >> 6;

    const float4* src4 = (const float4*)(src + ((size_t)b * 512 + part * 64) * 32);
    for (int i = tid; i < 64 * 8; i += 256) s_src[i] = src4[i];
    __syncthreads();
    if (tid < 64) {
        float a = 0.f;
#pragma unroll
        for (int q = 0; q < 8; q++) {
            float4 v = s_src[tid * 8 + q];
            a = fmaf(v.x, v.x, a); a = fmaf(v.y, v.y, a);
            a = fmaf(v.z, v.z, a); a = fmaf(v.w, v.w, a);
        }
        s_nrm[tid] = a;
    }
    __syncthreads();

    int t0 = wave * 64 + lane;
    int t1 = t0 + 256;
    v2f xd0[16], xd1[16];
    load_xd((const float4*)(dst + ((size_t)b * 512 + t0) * 32), xd0);
    load_xd((const float4*)(dst + ((size_t)b * 512 + t1) * 32), xd1);

    float val0[KNN], val1[KNN]; int idx0[KNN], idx1[KNN];
#pragma unroll
    for (int k = 0; k < KNN; k++) {
        val0[k] = 3.0e38f; idx0[k] = 0;
        val1[k] = 3.0e38f; idx1[k] = 0;
    }
    knn64_scan(s_src, s_nrm, xd0, xd1, val0, idx0, val1, idx1);

    int base = part * 64;
    {
        float* pv = pval + ((size_t)b * 512 + t0) * 64 + part * 8;
        unsigned int* pi = pidx + ((size_t)b * 512 + t0) * 32 + part * 4;
#pragma unroll
        for (int k = 0; k < KNN; k++) pv[k] = val0[k];
#pragma unroll
        for (int k = 0; k < 4; k++)
            pi[k] = (unsigned)(idx0[2*k] + base) | ((unsigned)(idx0[2*k+1] + base) << 16);
    }
    {
        float* pv = pval + ((size_t)b * 512 + t1) * 64 + part * 8;
        unsigned int* pi = pidx + ((size_t)b * 512 + t1) * 32 + part * 4;
#pragma unroll
        for (int k = 0; k < KNN; k++) pv[k] = val1[k];
#pragma unroll
        for (int k = 0; k < 4; k++)
            pi[k] = (unsigned)(idx1[2*k] + base) | ((unsigned)(idx1[2*k+1] + base) << 16);
    }
}

// ---------------- knn12: conv1 small + conv2 split (homogeneous) ----------
__global__ __launch_bounds__(256) void knn12_kernel(
    const float* __restrict__ sv_enc, const float* __restrict__ trk_enc,
    const float* __restrict__ pfc_enc,
    int* __restrict__ knn_idx,
    float* __restrict__ pval, unsigned int* __restrict__ pidx)
{
    int bid = blockIdx.x;            // 2304 = 256 small + 2048 split
    int r = bid % 9;
    if (r == 0) knn_small_body(sv_enc, trk_enc, knn_idx, bid / 9);
    else        knn_split_body(pfc_enc, trk_enc, pval, pidx, (bid / 9) * 8 + (r - 1));
}

__global__ __launch_bounds__(256) void knn3_kernel(
    const float* __restrict__ f1, const float* __restrict__ f2,
    float* __restrict__ pval, unsigned int* __restrict__ pidx)
{
    knn_split_body(f1, f2, pval, pidx, blockIdx.x);
}

// ---------------- Y/Base GEMM body (in-place-safe per 8-row tile) ---------
__device__ void yb_body(const float* __restrict__ X, const float* __restrict__ W,
                        const float* __restrict__ bias, float* __restrict__ O, int rb)
{
    __shared__ float sW[1024];
    __shared__ float sb[32];
    __shared__ float sx[8][32];
    int tid = threadIdx.x;
    for (int i = tid; i < 1024; i += 256) sW[i] = W[i];
    if (tid < 32) sb[tid] = bias ? bias[tid] : 0.f;
    int ln = tid >> 5, c = tid & 31;
    for (int p = 0; p < 8; p++) {
        __syncthreads();
        sx[ln][c] = X[(size_t)(rb + p * 8 + ln) * 32 + c];
        __syncthreads();
        float acc = sb[c];
#pragma unroll
        for (int d = 0; d < 32; d++) acc = fmaf(sx[ln][d], sW[d * 32 + c], acc);
        O[(size_t)(rb + p * 8 + ln) * 32 + c] = acc;
    }
}

// 6400 blocks: Y1 in-place sv(256) | B1->f1(2048) | Y2 in-place pfc(2048) | B2->f2(2048)
__global__ __launch_bounds__(256) void yb12_kernel(
    float* __restrict__ sv_enc, const float* __restrict__ trk_enc,
    float* __restrict__ pfc_enc,
    const float* __restrict__ w2h, const float* __restrict__ wd, const float* __restrict__ bb,
    float* __restrict__ f1, float* __restrict__ f2)
{
    int bid = blockIdx.x;
    if (bid < 256)       yb_body(sv_enc,  w2h, nullptr, sv_enc,  bid * 64);
    else if (bid < 2304) yb_body(trk_enc, wd,  bb,      f1, (bid - 256) * 64);
    else if (bid < 4352) yb_body(pfc_enc, w2h, nullptr, pfc_enc, (bid - 2304) * 64);
    else                 yb_body(trk_enc, wd,  bb,      f2, (bid - 4352) * 64);
}

// 4096 blocks: Y3 in-place f1(2048) | B3->f3(2048)
__global__ __launch_bounds__(256) void yb3_kernel(
    float* __restrict__ f1, const float* __restrict__ f2,
    const float* __restrict__ w2h, const float* __restrict__ wd, const float* __restrict__ bb,
    float* __restrict__ f3)
{
    int bid = blockIdx.x;
    if (bid < 2048) yb_body(f1, w2h, nullptr, f1, bid * 64);
    else            yb_body(f2, wd,  bb,      f3, (bid - 2048) * 64);
}

// ---------------- gather body: (8-part merge) + max + elu, in-place -------
template<bool MERGE>
__device__ void gather_body(
    const float* __restrict__ Y,
    const int* __restrict__ nbr,
    const float* __restrict__ pval, const unsigned int* __restrict__ pidx,
    float* __restrict__ f, int NSs, int t)
{
    int e = t >> 9;
    int rows[8];
    if (MERGE) {
        const float4* pv = (const float4*)(pval + (size_t)t * 64);
        const uint4*  pu = (const uint4*)(pidx + (size_t)t * 32);
        float4 v0 = pv[0], v1 = pv[1];
        uint4  u0 = pu[0];
        float val[8] = { v0.x, v0.y, v0.z, v0.w, v1.x, v1.y, v1.z, v1.w };
        int   idx[8] = { (int)(u0.x & 0xffff), (int)(u0.x >> 16),
                         (int)(u0.y & 0xffff), (int)(u0.y >> 16),
                         (int)(u0.z & 0xffff), (int)(u0.z >> 16),
                         (int)(u0.w & 0xffff), (int)(u0.w >> 16) };
#pragma unroll
        for (int p = 1; p < 8; p++) {
            float4 a = pv[2*p], b = pv[2*p+1];
            uint4  u = pu[p];
            float cva[8] = { a.x, a.y, a.z, a.w, b.x, b.y, b.z, b.w };
            int   cia[8] = { (int)(u.x & 0xffff), (int)(u.x >> 16),
                             (int)(u.y & 0xffff), (int)(u.y >> 16),
                             (int)(u.z & 0xffff), (int)(u.z >> 16),
                             (int)(u.w & 0xffff), (int)(u.w >> 16) };
#pragma unroll
            for (int j = 0; j < 8; j++) ins8(cva[j], cia[j], val, idx);
        }
#pragma unroll
        for (int k = 0; k < 8; k++) rows[k] = idx[k];
    } else {
        const int4* ip = (const int4*)(nbr + (size_t)t * 8);
        int4 i0 = ip[0], i1 = ip[1];
        rows[0] = i0.x; rows[1] = i0.y; rows[2] = i0.z; rows[3] = i0.w;
        rows[4] = i1.x; rows[5] = i1.y; rows[6] = i1.z; rows[7] = i1.w;
    }

    const float4* Yb = (const float4*)(Y + (size_t)e * NSs * 32);
    float4 m[8];
    {
        const float4* rr = Yb + (size_t)rows[0] * 8;
#pragma unroll
        for (int q = 0; q < 8; q++) m[q] = rr[q];
    }
#pragma unroll
    for (int k = 1; k < 8; k++) {
        const float4* rr = Yb + (size_t)rows[k] * 8;
#pragma unroll
        for (int q = 0; q < 8; q++) {
            float4 v = rr[q];
            m[q].x = fmaxf(m[q].x, v.x); m[q].y = fmaxf(m[q].y, v.y);
            m[q].z = fmaxf(m[q].z, v.z); m[q].w = fmaxf(m[q].w, v.w);
        }
    }
    float4* op = (float4*)(f + (size_t)t * 32);
#pragma unroll
    for (int q = 0; q < 8; q++) {
        float4 bv = op[q];
        float4 o;
        o.x = elu_f(bv.x + m[q].x); o.y = elu_f(bv.y + m[q].y);
        o.z = elu_f(bv.z + m[q].z); o.w = elu_f(bv.w + m[q].w);
        op[q] = o;
    }
}

// 1024 blocks: conv1 gather (512, no-merge, Y=sv_enc) + conv2 (512, merge, Y=pfc_enc)
__global__ __launch_bounds__(256) void g12_kernel(
    const float* __restrict__ Y1, const int* __restrict__ knn_idx, float* __restrict__ f1,
    const float* __restrict__ Y2, const float* __restrict__ pval,
    const unsigned int* __restrict__ pidx, float* __restrict__ f2)
{
    int bid = blockIdx.x;
    if (bid < 512) {
        int t = bid * 256 + threadIdx.x;
        gather_body<false>(Y1, knn_idx, nullptr, nullptr, f1, NSV, t);
    } else {
        int t = (bid - 512) * 256 + threadIdx.x;
        gather_body<true>(Y2, nullptr, pval, pidx, f2, NPFC, t);
    }
}

__global__ __launch_bounds__(256) void g3_kernel(
    const float* __restrict__ Y3, const float* __restrict__ pval,
    const unsigned int* __restrict__ pidx, float* __restrict__ f3)
{
    int t = blockIdx.x * 256 + threadIdx.x;
    gather_body<true>(Y3, nullptr, pval, pidx, f3, NTRK, t);
}

// ---------------- mean pool + out MLP + sigmoid + arange ----------------
__global__ __launch_bounds__(64) void final_kernel(
    const float* __restrict__ f3,
    const float* __restrict__ W1, const float* __restrict__ b1,
    const float* __restrict__ W2, const float* __restrict__ b2,
    float* __restrict__ outp)
{
    int b = blockIdx.x;
    int lane = threadIdx.x;
    int c = lane & 31, hh = lane >> 5;
    const float* base = f3 + (size_t)b * 512 * 32;
    float s = 0.f;
    for (int r = hh; r < 512; r += 2) s += base[r * 32 + c];
    s += __shfl_xor(s, 32);
    float pooled = s * (1.0f / 512.0f);
    __shared__ float sp[32];
    __shared__ float sh1[32];
    if (lane < 32) sp[c] = pooled;
    __syncthreads();
    if (lane < 32) {
        float h = b1[c];
#pragma unroll
        for (int d = 0; d < 32; d++) h = fmaf(sp[d], W1[d * 32 + c], h);
        sh1[c] = elu_f(h);
    }
    __syncthreads();
    if (lane == 0) {
        float o = b2[0];
#pragma unroll
        for (int d = 0; d < 32; d++) o = fmaf(sh1[d], W2[d], o);
        o = 1.f / (1.f + __expf(-o));
        outp[b] = o;
        outp[NB + b] = (float)b;
    }
}

extern "C" void kernel_launch(void* const* d_in, const int* in_sizes, int n_in,
                              void* d_out, int out_size, void* d_ws, size_t ws_size,
                              hipStream_t stream) {
    const float* x_sv  = (const float*)d_in[0];
    const float* x_trk = (const float*)d_in[1];
    const float* x_pfc = (const float*)d_in[2];
    const float* sv_W1  = (const float*)d_in[6];
    const float* sv_b1  = (const float*)d_in[7];
    const float* sv_W2  = (const float*)d_in[8];
    const float* sv_b2  = (const float*)d_in[9];
    const float* trk_W1 = (const float*)d_in[10];
    const float* trk_b1 = (const float*)d_in[11];
    const float* trk_W2 = (const float*)d_in[12];
    const float* trk_b2 = (const float*)d_in[13];
    const float* pfc_W1 = (const float*)d_in[14];
    const float* pfc_b1 = (const float*)d_in[15];
    const float* pfc_W2 = (const float*)d_in[16];
    const float* pfc_b2 = (const float*)d_in[17];
    const float* conv_W = (const float*)d_in[18];
    const float* conv_b = (const float*)d_in[19];
    const float* out_W1 = (const float*)d_in[20];
    const float* out_b1 = (const float*)d_in[21];
    const float* out_W2 = (const float*)d_in[22];
    const float* out_b2 = (const float*)d_in[23];

    float* ws = (float*)d_ws;
    const size_t SV_E  = (size_t)NB * NSV * HD;    //   524288
    const size_t TRK_E = (size_t)NB * NTRK * HD;   //  4194304
    float* sv_enc  = ws;                 // becomes Y1 in-place after yb12
    float* trk_enc = sv_enc + SV_E;
    float* pfc_enc = trk_enc + TRK_E;    // becomes Y2 in-place after yb12
    float* f1      = pfc_enc + TRK_E;    // becomes Y3 in-place after yb3
    float* f2      = f1 + TRK_E;
    float* wd      = f2 + TRK_E;
    float* w2h     = wd + 1024;
    float* bb      = w2h + 1024;
    float* pval    = bb + 64;                                  // NB*512*64 floats
    unsigned int* pidx = (unsigned int*)(pval + (size_t)NB * 512 * 64); // NB*512*32 u32
    int*   knn_idx = (int*)(pidx + (size_t)NB * 512 * 32);     // NB*512*8 ints
    float* f3      = trk_enc;  // trk_enc dead after yb12 -> reuse

    encode_all_kernel<<<8705, 256, 0, stream>>>(
        x_sv, x_trk, x_pfc,
        sv_W1, sv_b1, sv_W2, sv_b2,
        trk_W1, trk_b1, trk_W2, trk_b2,
        pfc_W1, pfc_b1, pfc_W2, pfc_b2,
        conv_W, conv_b,
        sv_enc, trk_enc, pfc_enc, wd, w2h, bb);

    knn12_kernel<<<2304, 256, 0, stream>>>(sv_enc, trk_enc, pfc_enc, knn_idx, pval, pidx);
    yb12_kernel<<<6400, 256, 0, stream>>>(sv_enc, trk_enc, pfc_enc, w2h, wd, bb, f1, f2);
    g12_kernel<<<1024, 256, 0, stream>>>(sv_enc, knn_idx, f1, pfc_enc, pval, pidx, f2);

    knn3_kernel<<<2048, 256, 0, stream>>>(f1, f2, pval, pidx);
    yb3_kernel<<<4096, 256, 0, stream>>>(f1, f2, w2h, wd, bb, f3);
    g3_kernel<<<512, 256, 0, stream>>>(f1, pval, pidx, f3);

    final_kernel<<<NB, 64, 0, stream>>>(f3, out_W1, out_b1, out_W2, out_b2, (float*)d_out);
}

// Round 12
// 557.461 us; speedup vs baseline: 1.1889x; 1.1889x over previous
//
#include <hip/hip_runtime.h>
#include <math.h>

#define NB 256      // events
#define NSV 64
#define KNN 8

typedef float v2f __attribute__((ext_vector_type(2)));

__device__ __forceinline__ float elu_f(float x) {
    return x > 0.f ? x : __expf(x) - 1.f;
}

// Branchless sorted top-8 insert (ascending val, lower-index tie-break via
// strict <; candidates presented in idx-ascending order among equal vals).
__device__ __forceinline__ void ins8(float dv, int s, float* val, int* idx) {
    bool c0 = dv < val[0], c1 = dv < val[1], c2 = dv < val[2], c3 = dv < val[3];
    bool c4 = dv < val[4], c5 = dv < val[5], c6 = dv < val[6], c7 = dv < val[7];
    val[7] = c6 ? val[6] : (c7 ? dv : val[7]);
    idx[7] = c6 ? idx[6] : (c7 ? s  : idx[7]);
    val[6] = c5 ? val[5] : (c6 ? dv : val[6]);
    idx[6] = c5 ? idx[5] : (c6 ? s  : idx[6]);
    val[5] = c4 ? val[4] : (c5 ? dv : val[5]);
    idx[5] = c4 ? idx[4] : (c5 ? s  : idx[5]);
    val[4] = c3 ? val[3] : (c4 ? dv : val[4]);
    idx[4] = c3 ? idx[3] : (c4 ? s  : idx[4]);
    val[3] = c2 ? val[2] : (c3 ? dv : val[3]);
    idx[3] = c2 ? idx[2] : (c3 ? s  : idx[3]);
    val[2] = c1 ? val[1] : (c2 ? dv : val[2]);
    idx[2] = c1 ? idx[1] : (c2 ? s  : idx[2]);
    val[1] = c0 ? val[0] : (c1 ? dv : val[1]);
    idx[1] = c0 ? idx[0] : (c1 ? s  : idx[1]);
    val[0] = c0 ? dv : val[0];
    idx[0] = c0 ? s  : idx[0];
}

// ================= fused encoder (+ conv-side linear precomputes) =========
// 64 nodes/block, 256 threads (thread = node-group g, col c; 8 nodes/thread).
// EXTRA=1: also write e1 = enc @ w2h (Y buffer, no bias)
// EXTRA=2: also write e1 = e2 = enc @ wd + cb (shared conv1/conv2 Base)
// Shared mem passed in (single kernel-level allocation; avoids per-template
// duplicate __shared__ blowing the LDS budget).
template<int FIN, int EXTRA>
__device__ void encode64_body(const float* __restrict__ x,
    const float* __restrict__ W1, const float* __restrict__ b1,
    const float* __restrict__ W2, const float* __restrict__ b2,
    const float* __restrict__ conv_W, const float* __restrict__ conv_b,
    float* __restrict__ enc, float* __restrict__ e1, float* __restrict__ e2,
    int blk, float* smem)
{
    float* sx  = smem;              // up to 64*30
    float* sW1 = sx + 64 * 30;      // up to 30*32
    float* sW2 = sW1 + 30 * 32;     // 1024
    float* sWe = sW2 + 1024;        // 1024
    float* sb1 = sWe + 1024;
    float* sb2 = sb1 + 32;
    float* sbe = sb2 + 32;
    float* sh  = sbe + 32;          // 2048
    int tid = threadIdx.x;
    for (int i = tid; i < FIN * 32; i += 256) sW1[i] = W1[i];
    for (int i = tid; i < 1024; i += 256) sW2[i] = W2[i];
    if (EXTRA == 1) for (int i = tid; i < 1024; i += 256) sWe[i] = conv_W[1024 + i];
    if (EXTRA == 2) for (int i = tid; i < 1024; i += 256) sWe[i] = conv_W[i] - conv_W[1024 + i];
    if (tid < 32) {
        sb1[tid] = b1[tid]; sb2[tid] = b2[tid];
        sbe[tid] = (EXTRA == 2) ? conv_b[tid] : 0.f;
    }
    size_t node0 = (size_t)blk * 64;
    for (int i = tid; i < 64 * FIN; i += 256) sx[i] = x[node0 * FIN + i];
    __syncthreads();
    int g = tid >> 5, c = tid & 31;
    float o[8];
#pragma unroll
    for (int j = 0; j < 8; j++) {
        int n = g * 8 + j;
        float a = sb1[c];
#pragma unroll
        for (int f = 0; f < FIN; f++) a = fmaf(sx[n * FIN + f], sW1[f * 32 + c], a);
        sh[n * 32 + c] = elu_f(a);
    }
    __syncthreads();
#pragma unroll
    for (int j = 0; j < 8; j++) {
        int n = g * 8 + j;
        float a = sb2[c];
#pragma unroll
        for (int k = 0; k < 32; k++) a = fmaf(sh[n * 32 + k], sW2[k * 32 + c], a);
        o[j] = elu_f(a);
        enc[(node0 + n) * 32 + c] = o[j];
    }
    if (EXTRA == 0) return;
    __syncthreads();
#pragma unroll
    for (int j = 0; j < 8; j++) sh[(g * 8 + j) * 32 + c] = o[j];
    __syncthreads();
#pragma unroll
    for (int j = 0; j < 8; j++) {
        int n = g * 8 + j;
        float a = sbe[c];
#pragma unroll
        for (int d = 0; d < 32; d++) a = fmaf(sh[n * 32 + d], sWe[d * 32 + c], a);
        size_t off = (node0 + n) * 32 + c;
        e1[off] = a;
        if (EXTRA == 2) e2[off] = a;
    }
}

// 4352 blocks: sv(256) | trk(2048) | pfc(2048)
__global__ __launch_bounds__(256) void encode_all_kernel(
    const float* __restrict__ x_sv, const float* __restrict__ x_trk, const float* __restrict__ x_pfc,
    const float* __restrict__ sv_W1, const float* __restrict__ sv_b1,
    const float* __restrict__ sv_W2, const float* __restrict__ sv_b2,
    const float* __restrict__ trk_W1, const float* __restrict__ trk_b1,
    const float* __restrict__ trk_W2, const float* __restrict__ trk_b2,
    const float* __restrict__ pfc_W1, const float* __restrict__ pfc_b1,
    const float* __restrict__ pfc_W2, const float* __restrict__ pfc_b2,
    const float* __restrict__ conv_W, const float* __restrict__ conv_b,
    float* __restrict__ sv_enc, float* __restrict__ trk_enc, float* __restrict__ pfc_enc,
    float* __restrict__ Y1, float* __restrict__ Y2,
    float* __restrict__ f1, float* __restrict__ f2)
{
    __shared__ float smem[64*30 + 30*32 + 1024 + 1024 + 96 + 2048];
    int bid = blockIdx.x;
    if (bid < 256)
        encode64_body<14, 1>(x_sv, sv_W1, sv_b1, sv_W2, sv_b2, conv_W, conv_b,
                             sv_enc, Y1, nullptr, bid, smem);
    else if (bid < 2304)
        encode64_body<30, 2>(x_trk, trk_W1, trk_b1, trk_W2, trk_b2, conv_W, conv_b,
                             trk_enc, f1, f2, bid - 256, smem);
    else
        encode64_body<10, 1>(x_pfc, pfc_W1, pfc_b1, pfc_W2, pfc_b2, conv_W, conv_b,
                             pfc_enc, Y2, nullptr, bid - 2304, smem);
}

// ================= kNN =====================================================
__device__ __forceinline__ void load_xd(const float4* xi, v2f* xd) {
#pragma unroll
    for (int q = 0; q < 8; q++) {
        float4 v = xi[q];
        xd[2*q]   = (v2f){v.x, v.y};
        xd[2*q+1] = (v2f){v.z, v.w};
    }
}

template<int NR>
__device__ void stage_rows(const float* __restrict__ src_rows,
                           float4* s_src, float* s_nrm, int tid)
{
    const float4* s4 = (const float4*)src_rows;
    for (int i = tid; i < NR * 8; i += 256) s_src[i] = s4[i];
    __syncthreads();
    for (int s = tid; s < NR; s += 256) {
        float a = 0.f;
#pragma unroll
        for (int q = 0; q < 8; q++) {
            float4 v = s_src[s * 8 + q];
            a = fmaf(v.x, v.x, a); a = fmaf(v.y, v.y, a);
            a = fmaf(v.z, v.z, a); a = fmaf(v.w, v.w, a);
        }
        s_nrm[s] = a;
    }
    __syncthreads();
}

// pk-fma scan: chains bit-identical to validated scalar rounds
// (a0:x a1:y a2:z a3:w; dv = nrm - 2*((a0+a1)+(a2+a3))).
template<int NR>
__device__ void knn_scan_core(const float4* __restrict__ s_src, const float* __restrict__ s_nrm,
                              const v2f* xd0, const v2f* xd1,
                              float* val0, int* idx0, float* val1, int* idx1)
{
    for (int s = 0; s < NR; s++) {
        v2f A01 = {0.f,0.f}, A23 = {0.f,0.f};
        v2f C01 = {0.f,0.f}, C23 = {0.f,0.f};
#pragma unroll
        for (int q = 0; q < 8; q++) {
            float4 v = s_src[s * 8 + q];
            v2f vxy = {v.x, v.y};
            v2f vzw = {v.z, v.w};
            A01 = __builtin_elementwise_fma(xd0[2*q],   vxy, A01);
            A23 = __builtin_elementwise_fma(xd0[2*q+1], vzw, A23);
            C01 = __builtin_elementwise_fma(xd1[2*q],   vxy, C01);
            C23 = __builtin_elementwise_fma(xd1[2*q+1], vzw, C23);
        }
        float nrm = s_nrm[s];
        float dv0 = nrm - 2.f * ((A01.x + A01.y) + (A23.x + A23.y));
        float dv1 = nrm - 2.f * ((C01.x + C01.y) + (C23.x + C23.y));
        ins8(dv0, s, val0, idx0);
        ins8(dv1, s, val1, idx1);
    }
}

// split part (128 rows): writes per-dst partial sorted top-8 (exact fp32 +
// u16 global idx). Merge in gather preserves single-scan tie semantics
// (parts merged in ascending-idx order; strict <).
__device__ void knn_split_body(const float* __restrict__ src, const float* __restrict__ dst,
                               float* __restrict__ pval, unsigned int* __restrict__ pidx,
                               int b, int part, float4* s_src, float* s_nrm)
{
    int tid = threadIdx.x, lane = tid & 63, wave = tid >> 6;
    stage_rows<128>(src + ((size_t)b * 512 + part * 128) * 32, s_src, s_nrm, tid);

    int t0 = wave * 64 + lane, t1 = t0 + 256;
    v2f xd0[16], xd1[16];
    load_xd((const float4*)(dst + ((size_t)b * 512 + t0) * 32), xd0);
    load_xd((const float4*)(dst + ((size_t)b * 512 + t1) * 32), xd1);

    float val0[8], val1[8]; int idx0[8], idx1[8];
#pragma unroll
    for (int k = 0; k < 8; k++) { val0[k] = 3.0e38f; idx0[k] = 0; val1[k] = 3.0e38f; idx1[k] = 0; }
    knn_scan_core<128>(s_src, s_nrm, xd0, xd1, val0, idx0, val1, idx1);

    int base = part * 128;
    for (int h = 0; h < 2; h++) {
        int t = h ? t1 : t0;
        const float* v = h ? val1 : val0;
        const int*   ix = h ? idx1 : idx0;
        float* pv = pval + ((size_t)b * 512 + t) * 32 + part * 8;
        unsigned int* pi = pidx + ((size_t)b * 512 + t) * 16 + part * 4;
#pragma unroll
        for (int k = 0; k < 8; k++) pv[k] = v[k];
#pragma unroll
        for (int k = 0; k < 4; k++)
            pi[k] = (unsigned)(ix[2*k] + base) | ((unsigned)(ix[2*k+1] + base) << 16);
    }
}

// conv1 small (64 src rows): final top-8 idx (u16) directly
__device__ void knn_small_body(const float* __restrict__ src, const float* __restrict__ dst,
                               unsigned short* __restrict__ idx1_out,
                               int b, float4* s_src, float* s_nrm)
{
    int tid = threadIdx.x, lane = tid & 63, wave = tid >> 6;
    stage_rows<64>(src + (size_t)b * 64 * 32, s_src, s_nrm, tid);

    int t0 = wave * 64 + lane, t1 = t0 + 256;
    v2f xd0[16], xd1[16];
    load_xd((const float4*)(dst + ((size_t)b * 512 + t0) * 32), xd0);
    load_xd((const float4*)(dst + ((size_t)b * 512 + t1) * 32), xd1);

    float val0[8], val1[8]; int idx0[8], idx1[8];
#pragma unroll
    for (int k = 0; k < 8; k++) { val0[k] = 3.0e38f; idx0[k] = 0; val1[k] = 3.0e38f; idx1[k] = 0; }
    knn_scan_core<64>(s_src, s_nrm, xd0, xd1, val0, idx0, val1, idx1);

    for (int h = 0; h < 2; h++) {
        int t = h ? t1 : t0;
        const int* ix = h ? idx1 : idx0;
        unsigned int* o32 = (unsigned int*)(idx1_out + ((size_t)b * 512 + t) * 8);
#pragma unroll
        for (int k = 0; k < 4; k++)
            o32[k] = (unsigned)ix[2*k] | ((unsigned)ix[2*k+1] << 16);
    }
}

// knn12: 1280 blocks. split conv2: bid<1024 (part=bid>>8, e=bid&255 — all
// parts of an event share bid%8 -> same-XCD L2 reuse of that event's dst
// rows). small conv1: bid in [1024,1280) dispatched last as tail-filler.
__global__ __launch_bounds__(256) void knn12_kernel(
    const float* __restrict__ sv_enc, const float* __restrict__ trk_enc,
    const float* __restrict__ pfc_enc,
    unsigned short* __restrict__ idx1_out,
    float* __restrict__ pval, unsigned int* __restrict__ pidx)
{
    __shared__ float4 s_src[128 * 8];
    __shared__ float  s_nrm[128];
    int bid = blockIdx.x;
    if (bid < 1024) knn_split_body(pfc_enc, trk_enc, pval, pidx, bid & 255, bid >> 8, s_src, s_nrm);
    else            knn_small_body(sv_enc, trk_enc, idx1_out, bid - 1024, s_src, s_nrm);
}

// knn3: 1024 blocks, 4-part split (same XCD swizzle)
__global__ __launch_bounds__(256) void knn3_kernel(
    const float* __restrict__ f1, const float* __restrict__ f2,
    float* __restrict__ pval, unsigned int* __restrict__ pidx)
{
    __shared__ float4 s_src[128 * 8];
    __shared__ float  s_nrm[128];
    int bid = blockIdx.x;
    knn_split_body(f1, f2, pval, pidx, bid & 255, bid >> 8, s_src, s_nrm);
}

// ================= gather helpers ==========================================
__device__ __forceinline__ void merge4(const float* __restrict__ pv_,
                                       const unsigned int* __restrict__ pu_, int* rows)
{
    const float4* pv = (const float4*)pv_;
    const uint4*  pu = (const uint4*)pu_;
    float4 v0 = pv[0], v1 = pv[1];
    uint4  u0 = pu[0];
    float val[8] = { v0.x, v0.y, v0.z, v0.w, v1.x, v1.y, v1.z, v1.w };
    int   idx[8] = { (int)(u0.x & 0xffff), (int)(u0.x >> 16),
                     (int)(u0.y & 0xffff), (int)(u0.y >> 16),
                     (int)(u0.z & 0xffff), (int)(u0.z >> 16),
                     (int)(u0.w & 0xffff), (int)(u0.w >> 16) };
#pragma unroll
    for (int p = 1; p < 4; p++) {
        float4 a = pv[2*p], b = pv[2*p+1];
        uint4  u = pu[p];
        float cva[8] = { a.x, a.y, a.z, a.w, b.x, b.y, b.z, b.w };
        int   cia[8] = { (int)(u.x & 0xffff), (int)(u.x >> 16),
                         (int)(u.y & 0xffff), (int)(u.y >> 16),
                         (int)(u.z & 0xffff), (int)(u.z >> 16),
                         (int)(u.w & 0xffff), (int)(u.w >> 16) };
#pragma unroll
        for (int j = 0; j < 8; j++) ins8(cva[j], cia[j], val, idx);
    }
#pragma unroll
    for (int k = 0; k < 8; k++) rows[k] = idx[k];
}

__device__ __forceinline__ void maxgather(const float* __restrict__ Ybase,
                                          const int* rows, float4* m)
{
    const float4* Yb = (const float4*)Ybase;
    const float4* r0 = Yb + (size_t)rows[0] * 8;
#pragma unroll
    for (int q = 0; q < 8; q++) m[q] = r0[q];
#pragma unroll
    for (int k = 1; k < 8; k++) {
        const float4* rr = Yb + (size_t)rows[k] * 8;
#pragma unroll
        for (int q = 0; q < 8; q++) {
            float4 v = rr[q];
            m[q].x = fmaxf(m[q].x, v.x); m[q].y = fmaxf(m[q].y, v.y);
            m[q].z = fmaxf(m[q].z, v.z); m[q].w = fmaxf(m[q].w, v.w);
        }
    }
}

// g12: 1024 blocks. f holds Base (written by encode); in-place f=elu(f+maxY).
__global__ __launch_bounds__(256) void g12_kernel(
    const float* __restrict__ Y1, const unsigned short* __restrict__ idx1, float* __restrict__ f1,
    const float* __restrict__ Y2, const float* __restrict__ pval,
    const unsigned int* __restrict__ pidx, float* __restrict__ f2)
{
    int bid = blockIdx.x;
    int tid = threadIdx.x;
    int rows[8];
    float* fp;
    const float* Yb;
    int t;
    if (bid < 512) {
        t = bid * 256 + tid;
        uint4 u = *(const uint4*)(idx1 + (size_t)t * 8);
        rows[0] = (int)(u.x & 0xffff); rows[1] = (int)(u.x >> 16);
        rows[2] = (int)(u.y & 0xffff); rows[3] = (int)(u.y >> 16);
        rows[4] = (int)(u.z & 0xffff); rows[5] = (int)(u.z >> 16);
        rows[6] = (int)(u.w & 0xffff); rows[7] = (int)(u.w >> 16);
        Yb = Y1 + (size_t)(t >> 9) * 64 * 32;
        fp = f1 + (size_t)t * 32;
    } else {
        t = (bid - 512) * 256 + tid;
        merge4(pval + (size_t)t * 32, pidx + (size_t)t * 16, rows);
        Yb = Y2 + (size_t)(t >> 9) * 512 * 32;
        fp = f2 + (size_t)t * 32;
    }
    float4 m[8];
    maxgather(Yb, rows, m);
    float4* op = (float4*)fp;
#pragma unroll
    for (int q = 0; q < 8; q++) {
        float4 bv = op[q];
        float4 o;
        o.x = elu_f(bv.x + m[q].x); o.y = elu_f(bv.y + m[q].y);
        o.z = elu_f(bv.z + m[q].z); o.w = elu_f(bv.w + m[q].w);
        op[q] = o;
    }
}

// yb3: 4096 blocks: Y3 = f1@w2h (bid<2048) | B3 = f2@wd+bb
__global__ __launch_bounds__(256) void yb3_kernel(
    const float* __restrict__ f1, const float* __restrict__ f2,
    const float* __restrict__ conv_W, const float* __restrict__ conv_b,
    float* __restrict__ Y3, float* __restrict__ B3)
{
    __shared__ float sW[1024];
    __shared__ float sb[32];
    __shared__ float sx[8][32];
    int bid = blockIdx.x;
    int tid = threadIdx.x;
    int mode = (bid >= 2048);
    const float* X = mode ? f2 : f1;
    float* O = mode ? B3 : Y3;
    int rb = (mode ? bid - 2048 : bid) * 64;
    for (int i = tid; i < 1024; i += 256)
        sW[i] = mode ? (conv_W[i] - conv_W[1024 + i]) : conv_W[1024 + i];
    if (tid < 32) sb[tid] = mode ? conv_b[tid] : 0.f;
    int ln = tid >> 5, c = tid & 31;
    for (int p = 0; p < 8; p++) {
        __syncthreads();
        sx[ln][c] = X[(size_t)(rb + p * 8 + ln) * 32 + c];
        __syncthreads();
        float acc = sb[c];
#pragma unroll
        for (int d = 0; d < 32; d++) acc = fmaf(sx[ln][d], sW[d * 32 + c], acc);
        O[(size_t)(rb + p * 8 + ln) * 32 + c] = acc;
    }
}

// g3: 512 blocks. Computes f3 rows in registers (never materialized) and
// reduces straight into per-block pooled partials (butterfly + LDS).
__global__ __launch_bounds__(256) void g3_kernel(
    const float* __restrict__ Y3, const float* __restrict__ B3,
    const float* __restrict__ pval, const unsigned int* __restrict__ pidx,
    float* __restrict__ pool)
{
    __shared__ float sp[4][32];
    int bid = blockIdx.x;
    int tid = threadIdx.x, lane = tid & 63, wave = tid >> 6;
    int t = bid * 256 + tid;
    int e = t >> 9;
    int rows[8];
    merge4(pval + (size_t)t * 32, pidx + (size_t)t * 16, rows);
    float4 m[8];
    maxgather(Y3 + (size_t)e * 512 * 32, rows, m);
    const float4* bp = (const float4*)(B3 + (size_t)t * 32);
    float4 r[8];
#pragma unroll
    for (int q = 0; q < 8; q++) {
        float4 bv = bp[q];
        r[q].x = elu_f(bv.x + m[q].x); r[q].y = elu_f(bv.y + m[q].y);
        r[q].z = elu_f(bv.z + m[q].z); r[q].w = elu_f(bv.w + m[q].w);
    }
    // wave butterfly sum of the 64 rows
    for (int off = 1; off < 64; off <<= 1) {
#pragma unroll
        for (int q = 0; q < 8; q++) {
            r[q].x += __shfl_xor(r[q].x, off);
            r[q].y += __shfl_xor(r[q].y, off);
            r[q].z += __shfl_xor(r[q].z, off);
            r[q].w += __shfl_xor(r[q].w, off);
        }
    }
    if (lane == 0) {
#pragma unroll
        for (int q = 0; q < 8; q++) {
            sp[wave][q*4+0] = r[q].x; sp[wave][q*4+1] = r[q].y;
            sp[wave][q*4+2] = r[q].z; sp[wave][q*4+3] = r[q].w;
        }
    }
    __syncthreads();
    if (tid < 32)
        pool[(size_t)bid * 32 + tid] = sp[0][tid] + sp[1][tid] + sp[2][tid] + sp[3][tid];
}

// final: tiny — 2 pooled partials per event + MLP + sigmoid + arange
__global__ __launch_bounds__(64) void final_kernel(
    const float* __restrict__ pool,
    const float* __restrict__ W1, const float* __restrict__ b1,
    const float* __restrict__ W2, const float* __restrict__ b2,
    float* __restrict__ outp)
{
    int b = blockIdx.x;
    int lane = threadIdx.x, c = lane & 31;
    __shared__ float sp[32];
    __shared__ float sh1[32];
    if (lane < 32)
        sp[c] = (pool[(size_t)(2*b) * 32 + c] + pool[(size_t)(2*b+1) * 32 + c]) * (1.0f / 512.0f);
    __syncthreads();
    if (lane < 32) {
        float h = b1[c];
#pragma unroll
        for (int d = 0; d < 32; d++) h = fmaf(sp[d], W1[d * 32 + c], h);
        sh1[c] = elu_f(h);
    }
    __syncthreads();
    if (lane == 0) {
        float o = b2[0];
#pragma unroll
        for (int d = 0; d < 32; d++) o = fmaf(sh1[d], W2[d], o);
        o = 1.f / (1.f + __expf(-o));
        outp[b] = o;
        outp[NB + b] = (float)b;
    }
}

extern "C" void kernel_launch(void* const* d_in, const int* in_sizes, int n_in,
                              void* d_out, int out_size, void* d_ws, size_t ws_size,
                              hipStream_t stream) {
    const float* x_sv  = (const float*)d_in[0];
    const float* x_trk = (const float*)d_in[1];
    const float* x_pfc = (const float*)d_in[2];
    const float* sv_W1  = (const float*)d_in[6];
    const float* sv_b1  = (const float*)d_in[7];
    const float* sv_W2  = (const float*)d_in[8];
    const float* sv_b2  = (const float*)d_in[9];
    const float* trk_W1 = (const float*)d_in[10];
    const float* trk_b1 = (const float*)d_in[11];
    const float* trk_W2 = (const float*)d_in[12];
    const float* trk_b2 = (const float*)d_in[13];
    const float* pfc_W1 = (const float*)d_in[14];
    const float* pfc_b1 = (const float*)d_in[15];
    const float* pfc_W2 = (const float*)d_in[16];
    const float* pfc_b2 = (const float*)d_in[17];
    const float* conv_W = (const float*)d_in[18];
    const float* conv_b = (const float*)d_in[19];
    const float* out_W1 = (const float*)d_in[20];
    const float* out_b1 = (const float*)d_in[21];
    const float* out_W2 = (const float*)d_in[22];
    const float* out_b2 = (const float*)d_in[23];

    float* ws = (float*)d_ws;
    const size_t SV_E  = (size_t)NB * 64 * 32;     //   524288
    const size_t TRK_E = (size_t)NB * 512 * 32;    //  4194304
    float* sv_enc  = ws;                           // pool aliases after knn12
    float* trk_enc = sv_enc + SV_E;                // B3 aliases after knn12
    float* pfc_enc = trk_enc + TRK_E;              // Y3 aliases after knn12
    float* f1      = pfc_enc + TRK_E;
    float* f2      = f1 + TRK_E;
    float* Y1      = f2 + TRK_E;                   // SV_E
    float* Y2      = Y1 + SV_E;                    // TRK_E
    float* pval    = Y2 + TRK_E;                   // TRK_E floats (4-part x 8)
    unsigned int*   pidx = (unsigned int*)(pval + TRK_E);      // NB*512*16 u32
    unsigned short* idx1 = (unsigned short*)(pidx + (size_t)NB * 512 * 16); // NB*512*8 u16
    float* Y3   = pfc_enc;   // pfc_enc dead after knn12
    float* B3   = trk_enc;   // trk_enc dead after knn12
    float* pool = sv_enc;    // sv_enc dead after knn12

    encode_all_kernel<<<4352, 256, 0, stream>>>(
        x_sv, x_trk, x_pfc,
        sv_W1, sv_b1, sv_W2, sv_b2,
        trk_W1, trk_b1, trk_W2, trk_b2,
        pfc_W1, pfc_b1, pfc_W2, pfc_b2,
        conv_W, conv_b,
        sv_enc, trk_enc, pfc_enc, Y1, Y2, f1, f2);

    knn12_kernel<<<1280, 256, 0, stream>>>(sv_enc, trk_enc, pfc_enc, idx1, pval, pidx);
    g12_kernel<<<1024, 256, 0, stream>>>(Y1, idx1, f1, Y2, pval, pidx, f2);

    yb3_kernel<<<4096, 256, 0, stream>>>(f1, f2, conv_W, conv_b, Y3, B3);
    knn3_kernel<<<1024, 256, 0, stream>>>(f1, f2, pval, pidx);
    g3_kernel<<<512, 256, 0, stream>>>(Y3, B3, pval, pidx, pool);

    final_kernel<<<NB, 64, 0, stream>>>(pool, out_W1, out_b1, out_W2, out_b2, (float*)d_out);
}

// Round 13
// 504.228 us; speedup vs baseline: 1.3144x; 1.1056x over previous
//
#include <hip/hip_runtime.h>
#include <math.h>

#define NB 256      // events
#define KNN 8

typedef float v2f __attribute__((ext_vector_type(2)));

__device__ __forceinline__ float elu_f(float x) {
    return x > 0.f ? x : __expf(x) - 1.f;
}

// ---- packed sort key: (monotone-u32(dv) & ~511) | global_row_idx ----------
// Ordering = (dv truncated to 512 ulp, then ascending idx). Distances stay
// exact fp32; only comparisons at <2^-14 relative granularity are fuzzed
// (tie-break remains lower-index-wins).
__device__ __forceinline__ unsigned fkey(float dv, int s) {
    unsigned u = __float_as_uint(dv);
    u = ((int)u < 0) ? ~u : (u | 0x80000000u);
    return (u & 0xFFFFFE00u) | (unsigned)s;
}

// compare-exchange insert into ascending sorted 8-list: 16 v_min/v_max_u32.
__device__ __forceinline__ void ce8(unsigned x, unsigned* v) {
#pragma unroll
    for (int k = 0; k < 8; k++) {
        unsigned lo = min(v[k], x);
        x = max(v[k], x);
        v[k] = lo;
    }
}

// ================= fused encoder (+ conv-side linear precomputes) =========
template<int FIN, int EXTRA>
__device__ void encode64_body(const float* __restrict__ x,
    const float* __restrict__ W1, const float* __restrict__ b1,
    const float* __restrict__ W2, const float* __restrict__ b2,
    const float* __restrict__ conv_W, const float* __restrict__ conv_b,
    float* __restrict__ enc, float* __restrict__ e1, float* __restrict__ e2,
    int blk, float* smem)
{
    float* sx  = smem;              // up to 64*30
    float* sW1 = sx + 64 * 30;      // up to 30*32
    float* sW2 = sW1 + 30 * 32;     // 1024
    float* sWe = sW2 + 1024;        // 1024
    float* sb1 = sWe + 1024;
    float* sb2 = sb1 + 32;
    float* sbe = sb2 + 32;
    float* sh  = sbe + 32;          // 2048
    int tid = threadIdx.x;
    for (int i = tid; i < FIN * 32; i += 256) sW1[i] = W1[i];
    for (int i = tid; i < 1024; i += 256) sW2[i] = W2[i];
    if (EXTRA == 1) for (int i = tid; i < 1024; i += 256) sWe[i] = conv_W[1024 + i];
    if (EXTRA == 2) for (int i = tid; i < 1024; i += 256) sWe[i] = conv_W[i] - conv_W[1024 + i];
    if (tid < 32) {
        sb1[tid] = b1[tid]; sb2[tid] = b2[tid];
        sbe[tid] = (EXTRA == 2) ? conv_b[tid] : 0.f;
    }
    size_t node0 = (size_t)blk * 64;
    for (int i = tid; i < 64 * FIN; i += 256) sx[i] = x[node0 * FIN + i];
    __syncthreads();
    int g = tid >> 5, c = tid & 31;
    float o[8];
#pragma unroll
    for (int j = 0; j < 8; j++) {
        int n = g * 8 + j;
        float a = sb1[c];
#pragma unroll
        for (int f = 0; f < FIN; f++) a = fmaf(sx[n * FIN + f], sW1[f * 32 + c], a);
        sh[n * 32 + c] = elu_f(a);
    }
    __syncthreads();
#pragma unroll
    for (int j = 0; j < 8; j++) {
        int n = g * 8 + j;
        float a = sb2[c];
#pragma unroll
        for (int k = 0; k < 32; k++) a = fmaf(sh[n * 32 + k], sW2[k * 32 + c], a);
        o[j] = elu_f(a);
        enc[(node0 + n) * 32 + c] = o[j];
    }
    if (EXTRA == 0) return;
    __syncthreads();
#pragma unroll
    for (int j = 0; j < 8; j++) sh[(g * 8 + j) * 32 + c] = o[j];
    __syncthreads();
#pragma unroll
    for (int j = 0; j < 8; j++) {
        int n = g * 8 + j;
        float a = sbe[c];
#pragma unroll
        for (int d = 0; d < 32; d++) a = fmaf(sh[n * 32 + d], sWe[d * 32 + c], a);
        size_t off = (node0 + n) * 32 + c;
        e1[off] = a;
        if (EXTRA == 2) e2[off] = a;
    }
}

// 4352 blocks: sv(256) | trk(2048) | pfc(2048)
__global__ __launch_bounds__(256) void encode_all_kernel(
    const float* __restrict__ x_sv, const float* __restrict__ x_trk, const float* __restrict__ x_pfc,
    const float* __restrict__ sv_W1, const float* __restrict__ sv_b1,
    const float* __restrict__ sv_W2, const float* __restrict__ sv_b2,
    const float* __restrict__ trk_W1, const float* __restrict__ trk_b1,
    const float* __restrict__ trk_W2, const float* __restrict__ trk_b2,
    const float* __restrict__ pfc_W1, const float* __restrict__ pfc_b1,
    const float* __restrict__ pfc_W2, const float* __restrict__ pfc_b2,
    const float* __restrict__ conv_W, const float* __restrict__ conv_b,
    float* __restrict__ sv_enc, float* __restrict__ trk_enc, float* __restrict__ pfc_enc,
    float* __restrict__ Y1, float* __restrict__ Y2,
    float* __restrict__ f1, float* __restrict__ f2)
{
    __shared__ float smem[64*30 + 30*32 + 1024 + 1024 + 96 + 2048];
    int bid = blockIdx.x;
    if (bid < 256)
        encode64_body<14, 1>(x_sv, sv_W1, sv_b1, sv_W2, sv_b2, conv_W, conv_b,
                             sv_enc, Y1, nullptr, bid, smem);
    else if (bid < 2304)
        encode64_body<30, 2>(x_trk, trk_W1, trk_b1, trk_W2, trk_b2, conv_W, conv_b,
                             trk_enc, f1, f2, bid - 256, smem);
    else
        encode64_body<10, 1>(x_pfc, pfc_W1, pfc_b1, pfc_W2, pfc_b2, conv_W, conv_b,
                             pfc_enc, Y2, nullptr, bid - 2304, smem);
}

// ================= kNN =====================================================
__device__ __forceinline__ void load_xd(const float4* xi, v2f* xd) {
#pragma unroll
    for (int q = 0; q < 8; q++) {
        float4 v = xi[q];
        xd[2*q]   = (v2f){v.x, v.y};
        xd[2*q+1] = (v2f){v.z, v.w};
    }
}

template<int NR>
__device__ void stage_rows(const float* __restrict__ src_rows,
                           float4* s_src, float* s_nrm, int tid)
{
    const float4* s4 = (const float4*)src_rows;
    for (int i = tid; i < NR * 8; i += 256) s_src[i] = s4[i];
    __syncthreads();
    for (int s = tid; s < NR; s += 256) {
        float a = 0.f;
#pragma unroll
        for (int q = 0; q < 8; q++) {
            float4 v = s_src[s * 8 + q];
            a = fmaf(v.x, v.x, a); a = fmaf(v.y, v.y, a);
            a = fmaf(v.z, v.z, a); a = fmaf(v.w, v.w, a);
        }
        s_nrm[s] = a;
    }
    __syncthreads();
}

// pk-fma distance chains (exact fp32, identical to validated rounds) +
// CE key selection.
template<int NR>
__device__ void knn_scan_core(const float4* __restrict__ s_src, const float* __restrict__ s_nrm,
                              const v2f* xd0, const v2f* xd1,
                              unsigned* key0, unsigned* key1, int base)
{
    for (int s = 0; s < NR; s++) {
        v2f A01 = {0.f,0.f}, A23 = {0.f,0.f};
        v2f C01 = {0.f,0.f}, C23 = {0.f,0.f};
#pragma unroll
        for (int q = 0; q < 8; q++) {
            float4 v = s_src[s * 8 + q];
            v2f vxy = {v.x, v.y};
            v2f vzw = {v.z, v.w};
            A01 = __builtin_elementwise_fma(xd0[2*q],   vxy, A01);
            A23 = __builtin_elementwise_fma(xd0[2*q+1], vzw, A23);
            C01 = __builtin_elementwise_fma(xd1[2*q],   vxy, C01);
            C23 = __builtin_elementwise_fma(xd1[2*q+1], vzw, C23);
        }
        float nrm = s_nrm[s];
        float dv0 = nrm - 2.f * ((A01.x + A01.y) + (A23.x + A23.y));
        float dv1 = nrm - 2.f * ((C01.x + C01.y) + (C23.x + C23.y));
        ce8(fkey(dv0, base + s), key0);
        ce8(fkey(dv1, base + s), key1);
    }
}

// split part (128 rows): per-dst partial sorted top-8 keys (global idx in key)
__device__ void knn_split_body(const float* __restrict__ src, const float* __restrict__ dst,
                               unsigned* __restrict__ pkey,
                               int b, int part, float4* s_src, float* s_nrm)
{
    int tid = threadIdx.x, lane = tid & 63, wave = tid >> 6;
    stage_rows<128>(src + ((size_t)b * 512 + part * 128) * 32, s_src, s_nrm, tid);

    int t0 = wave * 64 + lane, t1 = t0 + 256;
    v2f xd0[16], xd1[16];
    load_xd((const float4*)(dst + ((size_t)b * 512 + t0) * 32), xd0);
    load_xd((const float4*)(dst + ((size_t)b * 512 + t1) * 32), xd1);

    unsigned key0[8], key1[8];
#pragma unroll
    for (int k = 0; k < 8; k++) { key0[k] = 0xFFFFFFFFu; key1[k] = 0xFFFFFFFFu; }
    knn_scan_core<128>(s_src, s_nrm, xd0, xd1, key0, key1, part * 128);

    unsigned* p0 = pkey + ((size_t)b * 512 + t0) * 32 + part * 8;
    unsigned* p1 = pkey + ((size_t)b * 512 + t1) * 32 + part * 8;
#pragma unroll
    for (int k = 0; k < 8; k++) { p0[k] = key0[k]; p1[k] = key1[k]; }
}

// conv1 small (64 src rows): final top-8 idx (u16) directly
__device__ void knn_small_body(const float* __restrict__ src, const float* __restrict__ dst,
                               unsigned short* __restrict__ idx1_out,
                               int b, float4* s_src, float* s_nrm)
{
    int tid = threadIdx.x, lane = tid & 63, wave = tid >> 6;
    stage_rows<64>(src + (size_t)b * 64 * 32, s_src, s_nrm, tid);

    int t0 = wave * 64 + lane, t1 = t0 + 256;
    v2f xd0[16], xd1[16];
    load_xd((const float4*)(dst + ((size_t)b * 512 + t0) * 32), xd0);
    load_xd((const float4*)(dst + ((size_t)b * 512 + t1) * 32), xd1);

    unsigned key0[8], key1[8];
#pragma unroll
    for (int k = 0; k < 8; k++) { key0[k] = 0xFFFFFFFFu; key1[k] = 0xFFFFFFFFu; }
    knn_scan_core<64>(s_src, s_nrm, xd0, xd1, key0, key1, 0);

    for (int h = 0; h < 2; h++) {
        int t = h ? t1 : t0;
        const unsigned* kk = h ? key1 : key0;
        unsigned int* o32 = (unsigned int*)(idx1_out + ((size_t)b * 512 + t) * 8);
#pragma unroll
        for (int k = 0; k < 4; k++)
            o32[k] = (kk[2*k] & 511u) | ((kk[2*k+1] & 511u) << 16);
    }
}

// knn12: 1280 blocks. conv2 split: bid<1024 (part=bid>>8, e=bid&255, XCD
// swizzle). conv1 small: tail blocks.
__global__ __launch_bounds__(256) void knn12_kernel(
    const float* __restrict__ sv_enc, const float* __restrict__ trk_enc,
    const float* __restrict__ pfc_enc,
    unsigned short* __restrict__ idx1_out,
    unsigned* __restrict__ pkey)
{
    __shared__ float4 s_src[128 * 8];
    __shared__ float  s_nrm[128];
    int bid = blockIdx.x;
    if (bid < 1024) knn_split_body(pfc_enc, trk_enc, pkey, bid & 255, bid >> 8, s_src, s_nrm);
    else            knn_small_body(sv_enc, trk_enc, idx1_out, bid - 1024, s_src, s_nrm);
}

__global__ __launch_bounds__(256) void knn3_kernel(
    const float* __restrict__ f1, const float* __restrict__ f2,
    unsigned* __restrict__ pkey)
{
    __shared__ float4 s_src[128 * 8];
    __shared__ float  s_nrm[128];
    int bid = blockIdx.x;
    knn_split_body(f1, f2, pkey, bid & 255, bid >> 8, s_src, s_nrm);
}

// ================= gather helpers ==========================================
// merge 4 sorted partial key-lists (ascending part order) -> final 8 rows
__device__ __forceinline__ void merge_parts(const unsigned* __restrict__ pk_, int* rows)
{
    const uint4* pk = (const uint4*)pk_;
    uint4 a0 = pk[0], a1 = pk[1];
    unsigned v[8] = { a0.x, a0.y, a0.z, a0.w, a1.x, a1.y, a1.z, a1.w };
#pragma unroll
    for (int p = 1; p < 4; p++) {
        uint4 b0 = pk[2*p], b1 = pk[2*p+1];
        ce8(b0.x, v); ce8(b0.y, v); ce8(b0.z, v); ce8(b0.w, v);
        ce8(b1.x, v); ce8(b1.y, v); ce8(b1.z, v); ce8(b1.w, v);
    }
#pragma unroll
    for (int k = 0; k < 8; k++) rows[k] = (int)(v[k] & 511u);
}

__device__ __forceinline__ void maxgather(const float* __restrict__ Ybase,
                                          const int* rows, float4* m)
{
    const float4* Yb = (const float4*)Ybase;
    const float4* r0 = Yb + (size_t)rows[0] * 8;
#pragma unroll
    for (int q = 0; q < 8; q++) m[q] = r0[q];
#pragma unroll
    for (int k = 1; k < 8; k++) {
        const float4* rr = Yb + (size_t)rows[k] * 8;
#pragma unroll
        for (int q = 0; q < 8; q++) {
            float4 v = rr[q];
            m[q].x = fmaxf(m[q].x, v.x); m[q].y = fmaxf(m[q].y, v.y);
            m[q].z = fmaxf(m[q].z, v.z); m[q].w = fmaxf(m[q].w, v.w);
        }
    }
}

// g12: 1024 blocks. f holds Base (written by encode); in-place f=elu(f+maxY).
__global__ __launch_bounds__(256) void g12_kernel(
    const float* __restrict__ Y1, const unsigned short* __restrict__ idx1, float* __restrict__ f1,
    const float* __restrict__ Y2, const unsigned* __restrict__ pkey, float* __restrict__ f2)
{
    int bid = blockIdx.x;
    int tid = threadIdx.x;
    int rows[8];
    float* fp;
    const float* Yb;
    int t;
    if (bid < 512) {
        t = bid * 256 + tid;
        uint4 u = *(const uint4*)(idx1 + (size_t)t * 8);
        rows[0] = (int)(u.x & 0xffff); rows[1] = (int)(u.x >> 16);
        rows[2] = (int)(u.y & 0xffff); rows[3] = (int)(u.y >> 16);
        rows[4] = (int)(u.z & 0xffff); rows[5] = (int)(u.z >> 16);
        rows[6] = (int)(u.w & 0xffff); rows[7] = (int)(u.w >> 16);
        Yb = Y1 + (size_t)(t >> 9) * 64 * 32;
        fp = f1 + (size_t)t * 32;
    } else {
        t = (bid - 512) * 256 + tid;
        merge_parts(pkey + (size_t)t * 32, rows);
        Yb = Y2 + (size_t)(t >> 9) * 512 * 32;
        fp = f2 + (size_t)t * 32;
    }
    float4 m[8];
    maxgather(Yb, rows, m);
    float4* op = (float4*)fp;
#pragma unroll
    for (int q = 0; q < 8; q++) {
        float4 bv = op[q];
        float4 o;
        o.x = elu_f(bv.x + m[q].x); o.y = elu_f(bv.y + m[q].y);
        o.z = elu_f(bv.z + m[q].z); o.w = elu_f(bv.w + m[q].w);
        op[q] = o;
    }
}

// yb3: 4096 blocks: Y3 = f1@w2h (bid<2048) | B3 = f2@wd+bb
__global__ __launch_bounds__(256) void yb3_kernel(
    const float* __restrict__ f1, const float* __restrict__ f2,
    const float* __restrict__ conv_W, const float* __restrict__ conv_b,
    float* __restrict__ Y3, float* __restrict__ B3)
{
    __shared__ float sW[1024];
    __shared__ float sb[32];
    __shared__ float sx[8][32];
    int bid = blockIdx.x;
    int tid = threadIdx.x;
    int mode = (bid >= 2048);
    const float* X = mode ? f2 : f1;
    float* O = mode ? B3 : Y3;
    int rb = (mode ? bid - 2048 : bid) * 64;
    for (int i = tid; i < 1024; i += 256)
        sW[i] = mode ? (conv_W[i] - conv_W[1024 + i]) : conv_W[1024 + i];
    if (tid < 32) sb[tid] = mode ? conv_b[tid] : 0.f;
    int ln = tid >> 5, c = tid & 31;
    for (int p = 0; p < 8; p++) {
        __syncthreads();
        sx[ln][c] = X[(size_t)(rb + p * 8 + ln) * 32 + c];
        __syncthreads();
        float acc = sb[c];
#pragma unroll
        for (int d = 0; d < 32; d++) acc = fmaf(sx[ln][d], sW[d * 32 + c], acc);
        O[(size_t)(rb + p * 8 + ln) * 32 + c] = acc;
    }
}

// g3: 512 blocks. f3 rows in registers, reduced straight to pooled partials.
__global__ __launch_bounds__(256) void g3_kernel(
    const float* __restrict__ Y3, const float* __restrict__ B3,
    const unsigned* __restrict__ pkey,
    float* __restrict__ pool)
{
    __shared__ float sp[4][32];
    int bid = blockIdx.x;
    int tid = threadIdx.x, lane = tid & 63, wave = tid >> 6;
    int t = bid * 256 + tid;
    int e = t >> 9;
    int rows[8];
    merge_parts(pkey + (size_t)t * 32, rows);
    float4 m[8];
    maxgather(Y3 + (size_t)e * 512 * 32, rows, m);
    const float4* bp = (const float4*)(B3 + (size_t)t * 32);
    float4 r[8];
#pragma unroll
    for (int q = 0; q < 8; q++) {
        float4 bv = bp[q];
        r[q].x = elu_f(bv.x + m[q].x); r[q].y = elu_f(bv.y + m[q].y);
        r[q].z = elu_f(bv.z + m[q].z); r[q].w = elu_f(bv.w + m[q].w);
    }
    for (int off = 1; off < 64; off <<= 1) {
#pragma unroll
        for (int q = 0; q < 8; q++) {
            r[q].x += __shfl_xor(r[q].x, off);
            r[q].y += __shfl_xor(r[q].y, off);
            r[q].z += __shfl_xor(r[q].z, off);
            r[q].w += __shfl_xor(r[q].w, off);
        }
    }
    if (lane == 0) {
#pragma unroll
        for (int q = 0; q < 8; q++) {
            sp[wave][q*4+0] = r[q].x; sp[wave][q*4+1] = r[q].y;
            sp[wave][q*4+2] = r[q].z; sp[wave][q*4+3] = r[q].w;
        }
    }
    __syncthreads();
    if (tid < 32)
        pool[(size_t)bid * 32 + tid] = sp[0][tid] + sp[1][tid] + sp[2][tid] + sp[3][tid];
}

// final: 2 pooled partials per event + MLP + sigmoid + arange
__global__ __launch_bounds__(64) void final_kernel(
    const float* __restrict__ pool,
    const float* __restrict__ W1, const float* __restrict__ b1,
    const float* __restrict__ W2, const float* __restrict__ b2,
    float* __restrict__ outp)
{
    int b = blockIdx.x;
    int lane = threadIdx.x, c = lane & 31;
    __shared__ float sp[32];
    __shared__ float sh1[32];
    if (lane < 32)
        sp[c] = (pool[(size_t)(2*b) * 32 + c] + pool[(size_t)(2*b+1) * 32 + c]) * (1.0f / 512.0f);
    __syncthreads();
    if (lane < 32) {
        float h = b1[c];
#pragma unroll
        for (int d = 0; d < 32; d++) h = fmaf(sp[d], W1[d * 32 + c], h);
        sh1[c] = elu_f(h);
    }
    __syncthreads();
    if (lane == 0) {
        float o = b2[0];
#pragma unroll
        for (int d = 0; d < 32; d++) o = fmaf(sh1[d], W2[d], o);
        o = 1.f / (1.f + __expf(-o));
        outp[b] = o;
        outp[NB + b] = (float)b;
    }
}

extern "C" void kernel_launch(void* const* d_in, const int* in_sizes, int n_in,
                              void* d_out, int out_size, void* d_ws, size_t ws_size,
                              hipStream_t stream) {
    const float* x_sv  = (const float*)d_in[0];
    const float* x_trk = (const float*)d_in[1];
    const float* x_pfc = (const float*)d_in[2];
    const float* sv_W1  = (const float*)d_in[6];
    const float* sv_b1  = (const float*)d_in[7];
    const float* sv_W2  = (const float*)d_in[8];
    const float* sv_b2  = (const float*)d_in[9];
    const float* trk_W1 = (const float*)d_in[10];
    const float* trk_b1 = (const float*)d_in[11];
    const float* trk_W2 = (const float*)d_in[12];
    const float* trk_b2 = (const float*)d_in[13];
    const float* pfc_W1 = (const float*)d_in[14];
    const float* pfc_b1 = (const float*)d_in[15];
    const float* pfc_W2 = (const float*)d_in[16];
    const float* pfc_b2 = (const float*)d_in[17];
    const float* conv_W = (const float*)d_in[18];
    const float* conv_b = (const float*)d_in[19];
    const float* out_W1 = (const float*)d_in[20];
    const float* out_b1 = (const float*)d_in[21];
    const float* out_W2 = (const float*)d_in[22];
    const float* out_b2 = (const float*)d_in[23];

    float* ws = (float*)d_ws;
    const size_t SV_E  = (size_t)NB * 64 * 32;     //   524288
    const size_t TRK_E = (size_t)NB * 512 * 32;    //  4194304
    float* sv_enc  = ws;                           // pool aliases after knn12
    float* trk_enc = sv_enc + SV_E;                // B3 aliases after knn12
    float* pfc_enc = trk_enc + TRK_E;              // Y3 aliases after knn12
    float* f1      = pfc_enc + TRK_E;
    float* f2      = f1 + TRK_E;
    float* Y1      = f2 + TRK_E;                   // SV_E
    float* Y2      = Y1 + SV_E;                    // TRK_E
    unsigned* pkey = (unsigned*)(Y2 + TRK_E);      // NB*512*32 u32 (4 parts x 8)
    unsigned short* idx1 = (unsigned short*)(pkey + TRK_E);    // NB*512*8 u16
    float* Y3   = pfc_enc;   // pfc_enc dead after knn12
    float* B3   = trk_enc;   // trk_enc dead after knn12
    float* pool = sv_enc;    // sv_enc dead after knn12

    encode_all_kernel<<<4352, 256, 0, stream>>>(
        x_sv, x_trk, x_pfc,
        sv_W1, sv_b1, sv_W2, sv_b2,
        trk_W1, trk_b1, trk_W2, trk_b2,
        pfc_W1, pfc_b1, pfc_W2, pfc_b2,
        conv_W, conv_b,
        sv_enc, trk_enc, pfc_enc, Y1, Y2, f1, f2);

    knn12_kernel<<<1280, 256, 0, stream>>>(sv_enc, trk_enc, pfc_enc, idx1, pkey);
    g12_kernel<<<1024, 256, 0, stream>>>(Y1, idx1, f1, Y2, pkey, f2);

    yb3_kernel<<<4096, 256, 0, stream>>>(f1, f2, conv_W, conv_b, Y3, B3);
    knn3_kernel<<<1024, 256, 0, stream>>>(f1, f2, pkey);
    g3_kernel<<<512, 256, 0, stream>>>(Y3, B3, pkey, pool);

    final_kernel<<<NB, 64, 0, stream>>>(pool, out_W1, out_b1, out_W2, out_b2, (float*)d_out);
}